// Round 1
// baseline (1155.846 us; speedup 1.0000x reference)
//
#include <hip/hip_runtime.h>
#include <hip/hip_bf16.h>

// Problem constants
// S1 = S2 = 1024, S3 = 32, R = 16
// ws layout (phase 1): [T: 32*1024*256 f32 = 33.5MB][Bmat: 256*1024 f32 = 1MB]
// ws layout (phase 2): [y1: 32*1024*1024 bf16 = 67MB]  (overwrites T/Bmat)
// d_out doubles as scratch for X (NCHW fp32, 134MB) before conv2 overwrites it.

// ---------- Kernel 1: T[k][i][c*16+b] = sum_a Z3[c][k][a] * Z1[a][i][b] ----------
__global__ __launch_bounds__(256) void t_kernel(const float* __restrict__ Z1,
                                                const float* __restrict__ Z3,
                                                float* __restrict__ T) {
    int g = blockIdx.x * 256 + threadIdx.x;       // 32*1024*256 = 8388608 total
    int b = g & 15;
    int c = (g >> 4) & 15;
    int i = (g >> 8) & 1023;
    int k = g >> 18;
    float s = 0.f;
    #pragma unroll
    for (int a = 0; a < 16; ++a) {
        s += Z3[(c * 32 + k) * 16 + a] * Z1[(a * 1024 + i) * 16 + b];
    }
    T[g] = s;
}

// ---------- Kernel 2: Bmat[(c*16+b)*1024 + j] = Z2[(b*1024 + j)*16 + c] ----------
__global__ __launch_bounds__(256) void bmat_kernel(const float* __restrict__ Z2,
                                                   float* __restrict__ Bm) {
    int g = blockIdx.x * 256 + threadIdx.x;       // 256*1024 = 262144 total
    int j = g & 1023;
    int b = (g >> 10) & 15;
    int c = g >> 14;
    Bm[g] = Z2[(b * 1024 + j) * 16 + c];
}

// ---------- Kernel 3: X[k][j][i] = sum_cb T[k][i][cb] * Bm[cb][j] ----------
// 64x64 output tile per block, K=256 in steps of 16, 4x4 microtile per thread.
__global__ __launch_bounds__(256) void gemm_kernel(const float* __restrict__ T,
                                                   const float* __restrict__ Bm,
                                                   float* __restrict__ X) {
    __shared__ float sB[16][64];   // sB[kc][jj] = Bm[kk+kc][j0+jj]
    __shared__ float sA[64][17];   // sA[ii][kc] = T[k][i0+ii][kk+kc]  (+1 pad)
    int tid = threadIdx.x;
    int tx = tid & 15, ty = tid >> 4;
    int i0 = blockIdx.x * 64, j0 = blockIdx.y * 64, k = blockIdx.z;
    const float* Tk = T + (size_t)k * 1024 * 256;
    float acc[4][4];
    #pragma unroll
    for (int r = 0; r < 4; ++r)
        #pragma unroll
        for (int s = 0; s < 4; ++s) acc[r][s] = 0.f;

    for (int kk = 0; kk < 256; kk += 16) {
        #pragma unroll
        for (int r = 0; r < 4; ++r) {
            int idx = tid + r * 256;
            sB[idx >> 6][idx & 63] = Bm[(kk + (idx >> 6)) * 1024 + j0 + (idx & 63)];
        }
        #pragma unroll
        for (int r = 0; r < 4; ++r) {
            int idx = tid + r * 256;
            sA[idx >> 4][idx & 15] = Tk[(size_t)(i0 + (idx >> 4)) * 256 + kk + (idx & 15)];
        }
        __syncthreads();
        #pragma unroll
        for (int kc = 0; kc < 16; ++kc) {
            float a[4], b[4];
            #pragma unroll
            for (int s = 0; s < 4; ++s) a[s] = sA[tx * 4 + s][kc];
            #pragma unroll
            for (int r = 0; r < 4; ++r) b[r] = sB[kc][ty * 4 + r];
            #pragma unroll
            for (int r = 0; r < 4; ++r)
                #pragma unroll
                for (int s = 0; s < 4; ++s) acc[r][s] += b[r] * a[s];
        }
        __syncthreads();
    }
    #pragma unroll
    for (int r = 0; r < 4; ++r) {
        int j = j0 + ty * 4 + r;
        #pragma unroll
        for (int s = 0; s < 4; ++s) {
            int i = i0 + tx * 4 + s;
            X[((size_t)k * 1024 + j) * 1024 + i] = acc[r][s];
        }
    }
}

// ---------- Conv 3x3 SAME + bias + LeakyReLU ----------
__device__ inline float ld_in(const float* p, size_t idx) { return p[idx]; }
__device__ inline float ld_in(const __hip_bfloat16* p, size_t idx) { return __bfloat162float(p[idx]); }

// Block: 16x16 pixel tile; each thread: pixel (i,j), all 32 output channels.
// PERM=false: out is bf16 NCHW (y1).  PERM=true: out is fp32 [j][i][k] (final).
template <typename IN_T, bool PERM>
__global__ __launch_bounds__(256) void conv_kernel(const IN_T* __restrict__ in,
                                                   const float* __restrict__ W,
                                                   const float* __restrict__ bias,
                                                   void* __restrict__ outv) {
    __shared__ float wl[32 * 9 * 32];   // [c][tap][o] — float4-readable per (c,tap)
    __shared__ float patch[18 * 18];
    int tid = threadIdx.x;
    int tx = tid & 15, ty = tid >> 4;
    int i0 = blockIdx.x * 16, j0 = blockIdx.y * 16;

    // Stage weights: coalesced global read, transposed LDS write.
    // W is OIHW flat: d = (o*32+c)*9 + tap  ->  wl[c*288 + tap*32 + o]
    for (int d = tid; d < 32 * 9 * 32; d += 256) {
        int tap = d % 9;
        int c = (d / 9) & 31;
        int o = d / 288;
        wl[c * 288 + tap * 32 + o] = W[d];
    }

    float acc[32];
    #pragma unroll
    for (int o = 0; o < 32; ++o) acc[o] = 0.f;

    for (int c = 0; c < 32; ++c) {
        __syncthreads();   // protects patch reuse (and wl staging on c==0)
        for (int idx = tid; idx < 324; idx += 256) {
            int p = idx / 18, q = idx - p * 18;
            int jj = j0 - 1 + p, ii = i0 - 1 + q;
            float v = 0.f;
            if ((unsigned)jj < 1024u && (unsigned)ii < 1024u)
                v = ld_in(in, ((size_t)c * 1024 + jj) * 1024 + ii);
            patch[idx] = v;
        }
        __syncthreads();
        #pragma unroll
        for (int tap = 0; tap < 9; ++tap) {
            float v = patch[(ty + tap / 3) * 18 + (tx + tap % 3)];
            const float4* w4 = (const float4*)&wl[(c * 9 + tap) * 32];
            #pragma unroll
            for (int o4 = 0; o4 < 8; ++o4) {
                float4 w = w4[o4];
                acc[o4 * 4 + 0] += w.x * v;
                acc[o4 * 4 + 1] += w.y * v;
                acc[o4 * 4 + 2] += w.z * v;
                acc[o4 * 4 + 3] += w.w * v;
            }
        }
    }

    int i = i0 + tx, j = j0 + ty;
    if (!PERM) {
        __hip_bfloat16* out = (__hip_bfloat16*)outv;
        #pragma unroll
        for (int o = 0; o < 32; ++o) {
            float v = acc[o] + bias[o];
            v = (v >= 0.f) ? v : 0.01f * v;
            out[((size_t)o * 1024 + j) * 1024 + i] = __float2bfloat16(v);
        }
    } else {
        float* out = (float*)outv;
        #pragma unroll
        for (int o = 0; o < 32; ++o) {
            float v = acc[o] + bias[o];
            v = (v >= 0.f) ? v : 0.01f * v;
            out[((size_t)j * 1024 + i) * 32 + o] = v;
        }
    }
}

extern "C" void kernel_launch(void* const* d_in, const int* in_sizes, int n_in,
                              void* d_out, int out_size, void* d_ws, size_t ws_size,
                              hipStream_t stream) {
    const float* Z1 = (const float*)d_in[0];
    const float* Z2 = (const float*)d_in[1];
    const float* Z3 = (const float*)d_in[2];
    const float* W1 = (const float*)d_in[3];
    const float* b1 = (const float*)d_in[4];
    const float* W2 = (const float*)d_in[5];
    const float* b2 = (const float*)d_in[6];

    float* X = (float*)d_out;                         // 32*1024*1024 f32 scratch, then final out
    float* Tbuf = (float*)d_ws;                       // 8.4M f32
    float* Bm = Tbuf + 32 * 1024 * 256;               // 256K f32
    __hip_bfloat16* y1 = (__hip_bfloat16*)d_ws;       // 33.5M bf16 (phase 2)

    t_kernel<<<32768, 256, 0, stream>>>(Z1, Z3, Tbuf);
    bmat_kernel<<<1024, 256, 0, stream>>>(Z2, Bm);
    gemm_kernel<<<dim3(16, 16, 32), 256, 0, stream>>>(Tbuf, Bm, X);
    conv_kernel<float, false><<<dim3(64, 64), 256, 0, stream>>>(X, W1, b1, y1);
    conv_kernel<__hip_bfloat16, true><<<dim3(64, 64), 256, 0, stream>>>(y1, W2, b2, d_out);
}

// Round 2
// 229.483 us; speedup vs baseline: 5.0367x; 5.0367x over previous
//
#include <hip/hip_runtime.h>

typedef short  s16x4 __attribute__((ext_vector_type(4)));
typedef short  s16x8 __attribute__((ext_vector_type(8)));
typedef float  f32x4 __attribute__((ext_vector_type(4)));

__device__ __forceinline__ unsigned short f2b(float f) {
    unsigned u = __float_as_uint(f);
    u = u + 0x7FFFu + ((u >> 16) & 1u);   // RNE
    return (unsigned short)(u >> 16);
}

__device__ __forceinline__ void gload16(const void* g, void* l) {
    __builtin_amdgcn_global_load_lds((const __attribute__((address_space(1))) unsigned*)g,
                                     (__attribute__((address_space(3))) unsigned*)l,
                                     16, 0, 0);
}

// slot swizzle, period 16 in x: f(x+16)==f(x)
__device__ __forceinline__ int swz(int x) { return (x ^ (x >> 2)) & 3; }

// ---------- T[k][i][cb] = sum_a Z3[c][k][a] * Z1[a][i][b], cb = c*16+b, bf16 out ----------
__global__ __launch_bounds__(256) void t_kernel(const float* __restrict__ Z1,
                                                const float* __restrict__ Z3,
                                                short* __restrict__ T) {
    __shared__ float z1s[256];    // [a][b] for this i
    __shared__ float z3s[8192];   // all of Z3: [c][k][a]
    const int tid = threadIdx.x;
    const int i = blockIdx.x;
    z1s[tid] = Z1[(tid >> 4) * 16384 + (i << 4) + (tid & 15)];   // Z1[a][i][b]
    for (int t = tid; t < 8192; t += 256) z3s[t] = Z3[t];
    __syncthreads();
    const int cb = tid, c = cb >> 4, b = cb & 15;
    for (int k = 0; k < 32; ++k) {
        float s = 0.f;
        #pragma unroll
        for (int a = 0; a < 16; ++a)
            s += z3s[c * 512 + k * 16 + a] * z1s[a * 16 + b];
        T[((size_t)k << 18) + (i << 8) + cb] = (short)f2b(s);
    }
}

// ---------- Bmt[j][cb] = Z2[b][j][c], bf16 ----------
__global__ __launch_bounds__(256) void bmat_kernel(const float* __restrict__ Z2,
                                                   short* __restrict__ Bm) {
    int g = blockIdx.x * 256 + threadIdx.x;   // g = j*256 + cb
    int cb = g & 255, j = g >> 8;
    int c = cb >> 4, b = cb & 15;
    Bm[g] = (short)f2b(Z2[((b << 10) + j) * 16 + c]);
}

// ---------- X[k][j][i] = sum_cb T[k][i][cb] * Bmt[j][cb]  (bf16 MFMA, 128x128 tile) ----------
__global__ __launch_bounds__(256) void gemm_kernel(const short* __restrict__ T,
                                                   const short* __restrict__ Bm,
                                                   short* __restrict__ X) {
    __shared__ short sA[128 * 32];   // [row i][kc] 64B rows, slot-swizzled
    __shared__ short sB[128 * 32];   // [row j][kc]
    const int tid = threadIdx.x;
    const int w = tid >> 6, lane = tid & 63, lane15 = lane & 15, q = lane >> 4;
    const int wm = w >> 1, wn = w & 1;
    const int i0 = blockIdx.x * 128, j0 = blockIdx.y * 128, k = blockIdx.z;
    const int rs = lane >> 2, sp = lane & 3;
    const int scol = (sp ^ swz(rs)) << 3;    // pre-swizzled source slot (elems)
    const int fl = swz(lane15);              // read-side swizzle

    const short* Ta = T + ((size_t)k << 18);

    f32x4 acc[4][4];
    #pragma unroll
    for (int a = 0; a < 4; ++a)
        #pragma unroll
        for (int b = 0; b < 4; ++b) acc[a][b] = (f32x4)0;

    for (int kk = 0; kk < 256; kk += 32) {
        gload16(&Ta[(i0 + w * 16 + rs) * 256 + kk + scol],       (char*)sA + w * 1024);
        gload16(&Ta[(i0 + (w + 4) * 16 + rs) * 256 + kk + scol], (char*)sA + (w + 4) * 1024);
        gload16(&Bm[(size_t)(j0 + w * 16 + rs) * 256 + kk + scol],       (char*)sB + w * 1024);
        gload16(&Bm[(size_t)(j0 + (w + 4) * 16 + rs) * 256 + kk + scol], (char*)sB + (w + 4) * 1024);
        __syncthreads();
        s16x8 af[4], bf[4];
        #pragma unroll
        for (int fm = 0; fm < 4; ++fm) {
            const int r = wm * 64 + fm * 16 + lane15;
            af[fm] = *(const s16x8*)&sA[r * 32 + ((q ^ fl) << 3)];
        }
        #pragma unroll
        for (int fn = 0; fn < 4; ++fn) {
            const int r = wn * 64 + fn * 16 + lane15;
            bf[fn] = *(const s16x8*)&sB[r * 32 + ((q ^ fl) << 3)];
        }
        #pragma unroll
        for (int fm = 0; fm < 4; ++fm)
            #pragma unroll
            for (int fn = 0; fn < 4; ++fn)
                acc[fm][fn] = __builtin_amdgcn_mfma_f32_16x16x32_bf16(af[fm], bf[fn], acc[fm][fn], 0, 0, 0);
        __syncthreads();
    }

    #pragma unroll
    for (int fm = 0; fm < 4; ++fm) {
        const int i4 = i0 + wm * 64 + fm * 16 + q * 4;   // D rows = i
        #pragma unroll
        for (int fn = 0; fn < 4; ++fn) {
            const int j = j0 + wn * 64 + fn * 16 + lane15;  // D col = j
            s16x4 p;
            #pragma unroll
            for (int r = 0; r < 4; ++r) p[r] = (short)f2b(acc[fm][fn][r]);
            *(s16x4*)&X[(((size_t)k << 10) + j) * 1024 + i4] = p;
        }
    }
}

// ---------- conv 3x3 SAME + bias + leaky, implicit GEMM (per-tap K=32 MFMA) ----------
// MODE 1: in = X NCHW bf16 (scatter-stage), out = y1 NHWC bf16
// MODE 2: in = y1 NHWC bf16 (global_load_lds stage), out = final NHWC fp32
template <int MODE>
__global__ __launch_bounds__(256) void conv_kernel(const short* __restrict__ in,
                                                   const float* __restrict__ Wr,
                                                   const float* __restrict__ bias,
                                                   void* __restrict__ outv) {
    constexpr int PXW  = (MODE == 1) ? 144 : 130;   // staged x width
    constexpr int XOFF = (MODE == 1) ? 7 : 0;       // LDS px of (out x0, dx=0) minus dx
    __shared__ short tile[6 * PXW * 32];            // [row][px][c], slot-swizzled
    const int tid = threadIdx.x;
    const int w = tid >> 6, lane = tid & 63, lane15 = lane & 15, q = lane >> 4;
    const int x0 = blockIdx.x * 128, y0 = blockIdx.y * 4;

    // A-fragments (weights) in registers: aw[tap][mf], A[o][c], o=mf*16+lane15, c=q*8+e
    s16x8 aw[9][2];
    #pragma unroll
    for (int t = 0; t < 9; ++t)
        #pragma unroll
        for (int mf = 0; mf < 2; ++mf) {
            const int o = mf * 16 + lane15;
            const int cb0 = q * 8;
            s16x8 a;
            #pragma unroll
            for (int e = 0; e < 8; ++e)
                a[e] = (short)f2b(Wr[(o * 32 + cb0 + e) * 9 + t]);
            aw[t][mf] = a;
        }

    const bool edge = (blockIdx.x == 0) | (blockIdx.x == 7) | (blockIdx.y == 0) | (blockIdx.y == 255);
    if (edge) {
        s16x8* t8 = (s16x8*)tile;
        for (int idx = tid; idx < 6 * PXW * 4; idx += 256) t8[idx] = (s16x8)0;
        __syncthreads();
    }

    if (MODE == 1) {
        // NCHW -> NHWC LDS: rows y0-1..y0+4, px x0-8..x0+135
        for (int idx = tid; idx < 6 * 18 * 32; idx += 256) {
            const int c = idx & 31;
            const int chunk = (idx >> 5) % 18;
            const int row = idx / (18 * 32);
            const int gy = y0 - 1 + row;
            const int gx = x0 - 8 + chunk * 8;
            if ((unsigned)gy < 1024u && (unsigned)gx < 1024u) {
                const s16x8 v = *(const s16x8*)&in[((size_t)c << 20) + ((size_t)gy << 10) + gx];
                const int lpx0 = chunk * 8;
                #pragma unroll
                for (int e = 0; e < 8; ++e) {
                    const int lpx = lpx0 + e;
                    tile[(row * PXW + lpx) * 32 + ((((c >> 3) ^ swz(lpx)) << 3) + (c & 7))] = v[e];
                }
            }
        }
    } else {
        // NHWC -> LDS via global_load_lds, pre-swizzled source
        for (int idx0 = 0; idx0 < 6 * PXW * 4; idx0 += 256) {
            const int idx = idx0 + tid;
            void* ldst = (void*)((char*)tile + (size_t)(idx0 + w * 64) * 16);
            if (idx < 6 * PXW * 4) {
                const int row = idx / (PXW * 4);
                const int rem = idx - row * (PXW * 4);
                const int px = rem >> 2, s = rem & 3;
                const int gy = y0 - 1 + row;
                const int gx = x0 - 1 + px;
                if ((unsigned)gy < 1024u && (unsigned)gx < 1024u)
                    gload16(&in[((((size_t)gy << 10) + gx) << 5) + ((s ^ swz(px)) << 3)], ldst);
            }
        }
    }
    __syncthreads();

    int flx[3];
    #pragma unroll
    for (int dx = 0; dx < 3; ++dx) flx[dx] = swz(lane15 + dx + XOFF);

    f32x4 acc[8][2];
    #pragma unroll
    for (int nf = 0; nf < 8; ++nf) { acc[nf][0] = (f32x4)0; acc[nf][1] = (f32x4)0; }

    #pragma unroll
    for (int t = 0; t < 9; ++t) {
        const int dy = t / 3, dx = t % 3;
        const int lbase = ((w + dy) * PXW + lane15 + dx + XOFF) * 32 + ((q ^ flx[dx]) << 3);
        #pragma unroll
        for (int nf = 0; nf < 8; ++nf) {
            const s16x8 bfr = *(const s16x8*)&tile[lbase + nf * 512];
            acc[nf][0] = __builtin_amdgcn_mfma_f32_16x16x32_bf16(aw[t][0], bfr, acc[nf][0], 0, 0, 0);
            acc[nf][1] = __builtin_amdgcn_mfma_f32_16x16x32_bf16(aw[t][1], bfr, acc[nf][1], 0, 0, 0);
        }
    }

    const int gy = y0 + w;
    #pragma unroll
    for (int mf = 0; mf < 2; ++mf) {
        const int o4 = mf * 16 + q * 4;                       // D rows = o
        const f32x4 bb = *(const f32x4*)&bias[o4];
        #pragma unroll
        for (int nf = 0; nf < 8; ++nf) {
            const int gx = x0 + nf * 16 + lane15;             // D col = pixel
            f32x4 v = acc[nf][mf];
            #pragma unroll
            for (int r = 0; r < 4; ++r) {
                v[r] += bb[r];
                v[r] = v[r] >= 0.f ? v[r] : 0.01f * v[r];
            }
            const size_t off = ((((size_t)gy << 10) + gx) << 5) + o4;
            if (MODE == 1) {
                s16x4 p;
                #pragma unroll
                for (int r = 0; r < 4; ++r) p[r] = (short)f2b(v[r]);
                *(s16x4*)((short*)outv + off) = p;
            } else {
                *(f32x4*)((float*)outv + off) = v;
            }
        }
    }
}

extern "C" void kernel_launch(void* const* d_in, const int* in_sizes, int n_in,
                              void* d_out, int out_size, void* d_ws, size_t ws_size,
                              hipStream_t stream) {
    const float* Z1 = (const float*)d_in[0];
    const float* Z2 = (const float*)d_in[1];
    const float* Z3 = (const float*)d_in[2];
    const float* W1 = (const float*)d_in[3];
    const float* b1 = (const float*)d_in[4];
    const float* W2 = (const float*)d_in[5];
    const float* b2 = (const float*)d_in[6];

    // d_out (134.2 MB) as scratch: [X nchw bf16 67.1MB][T bf16 16.8MB][Bmt bf16 0.5MB]
    short* Xs  = (short*)d_out;
    short* Ts  = Xs + 33554432;
    short* Bms = Ts + 8388608;
    short* y1  = (short*)d_ws;            // 67.1 MB NHWC bf16

    t_kernel<<<1024, 256, 0, stream>>>(Z1, Z3, Ts);
    bmat_kernel<<<1024, 256, 0, stream>>>(Z2, Bms);
    gemm_kernel<<<dim3(8, 8, 32), 256, 0, stream>>>(Ts, Bms, Xs);
    conv_kernel<1><<<dim3(8, 256), 256, 0, stream>>>(Xs, W1, b1, y1);
    conv_kernel<2><<<dim3(8, 256), 256, 0, stream>>>(y1, W2, b2, d_out);
}

// Round 3
// 203.153 us; speedup vs baseline: 5.6895x; 1.1296x over previous
//
#include <hip/hip_runtime.h>

typedef short  s16x4 __attribute__((ext_vector_type(4)));
typedef short  s16x8 __attribute__((ext_vector_type(8)));
typedef float  f32x4 __attribute__((ext_vector_type(4)));

__device__ __forceinline__ unsigned short f2b(float f) {
    unsigned u = __float_as_uint(f);
    u = u + 0x7FFFu + ((u >> 16) & 1u);   // RNE
    return (unsigned short)(u >> 16);
}

__device__ __forceinline__ void gload16(const void* g, void* l) {
    __builtin_amdgcn_global_load_lds((const __attribute__((address_space(1))) unsigned*)g,
                                     (__attribute__((address_space(3))) unsigned*)l,
                                     16, 0, 0);
}

// slot swizzle, period 16: maps px -> 16B-slot XOR so 16 consecutive px rows
// spread across banks (2-way max on ds_read_b128)
__device__ __forceinline__ int swz(int x) { return (x ^ (x >> 2)) & 3; }

// ---------- Bv2[(j*32+k)*256 + a*16+b] = sum_c Z2[b,j,c] * Z3[c,k,a]  (bf16) ----------
__global__ __launch_bounds__(256) void v_kernel(const float* __restrict__ Z2,
                                                const float* __restrict__ Z3,
                                                short* __restrict__ Bv2) {
    __shared__ float z3t[8192];   // [c][a][k] : c*512 + a*32 + k
    __shared__ float z2s[256];    // [b][c]
    const int tid = threadIdx.x, j = blockIdx.x;
    for (int t = tid; t < 8192; t += 256) {
        float v = Z3[t];                     // Z3[c,k,a] flat = c*512 + k*16 + a
        int c = t >> 9, k = (t >> 4) & 31, a = t & 15;
        z3t[c * 512 + a * 32 + k] = v;
    }
    z2s[tid] = Z2[(tid >> 4) * 16384 + j * 16 + (tid & 15)];   // [b][c]
    __syncthreads();
    const int a = tid >> 4, b = tid & 15;
    float z2r[16];
    #pragma unroll
    for (int c = 0; c < 16; ++c) z2r[c] = z2s[b * 16 + c];
    float s[32];
    #pragma unroll
    for (int k = 0; k < 32; ++k) s[k] = 0.f;
    #pragma unroll
    for (int c = 0; c < 16; ++c) {
        #pragma unroll
        for (int k4 = 0; k4 < 8; ++k4) {
            f32x4 v = *(const f32x4*)&z3t[c * 512 + a * 32 + k4 * 4];
            #pragma unroll
            for (int r = 0; r < 4; ++r) s[k4 * 4 + r] += z2r[c] * v[r];
        }
    }
    #pragma unroll
    for (int k = 0; k < 32; ++k)
        Bv2[(size_t)(j * 32 + k) * 256 + tid] = (short)f2b(s[k]);
}

// ---------- Z1r[i*256 + a*16+b] = Z1[a,i,b]  (bf16) ----------
__global__ __launch_bounds__(256) void z1r_kernel(const float* __restrict__ Z1,
                                                  short* __restrict__ Z1r) {
    __shared__ float z1s[4096];   // a*256 + il*16 + b
    const int tid = threadIdx.x, i0 = blockIdx.x * 16;
    #pragma unroll
    for (int a = 0; a < 16; ++a)
        z1s[a * 256 + tid] = Z1[a * 16384 + i0 * 16 + tid];
    __syncthreads();
    #pragma unroll
    for (int il = 0; il < 16; ++il)
        Z1r[(size_t)(i0 + il) * 256 + tid] =
            (short)f2b(z1s[(tid >> 4) * 256 + il * 16 + (tid & 15)]);
}

// ---------- X_nhwc[j][i][k] = sum_ab Bv2[(j*32+k)][ab] * Z1r[i][ab]  (bf16 MFMA) ----------
// M = n = j*32+k (32768), N = i (1024), K = 256.  128x128 tile, BK=32.
__global__ __launch_bounds__(256) void gemm_kernel(const short* __restrict__ Bv2,
                                                   const short* __restrict__ Z1r,
                                                   short* __restrict__ X) {
    __shared__ short sA[128 * 32];   // [n-local][kc], 64B rows, slot-swizzled
    __shared__ short sB[128 * 32];   // [i-local][kc]
    const int tid = threadIdx.x;
    const int w = tid >> 6, lane = tid & 63, lane15 = lane & 15, q = lane >> 4;
    const int wm = w >> 1, wn = w & 1;
    const int bid = blockIdx.x;
    const int l = (bid & 7) * 256 + (bid >> 3);      // XCD-chunked swizzle (2048 % 8 == 0)
    const int n0 = (l >> 3) * 128, i0 = (l & 7) * 128;
    const int rs = lane >> 2, sp = lane & 3;
    const int scol = (sp ^ swz(rs)) << 3;            // pre-swizzled source slot (elems)
    const int fl = swz(lane15);

    f32x4 acc[4][4];
    #pragma unroll
    for (int a = 0; a < 4; ++a)
        #pragma unroll
        for (int b = 0; b < 4; ++b) acc[a][b] = (f32x4)0;

    for (int kk = 0; kk < 256; kk += 32) {
        gload16(&Bv2[(size_t)(n0 + w * 16 + rs) * 256 + kk + scol],       (char*)sA + w * 1024);
        gload16(&Bv2[(size_t)(n0 + (w + 4) * 16 + rs) * 256 + kk + scol], (char*)sA + (w + 4) * 1024);
        gload16(&Z1r[(size_t)(i0 + w * 16 + rs) * 256 + kk + scol],       (char*)sB + w * 1024);
        gload16(&Z1r[(size_t)(i0 + (w + 4) * 16 + rs) * 256 + kk + scol], (char*)sB + (w + 4) * 1024);
        __syncthreads();
        s16x8 af[4], bf[4];
        #pragma unroll
        for (int fm = 0; fm < 4; ++fm) {
            const int r = wm * 64 + fm * 16 + lane15;
            af[fm] = *(const s16x8*)&sA[r * 32 + ((q ^ fl) << 3)];
        }
        #pragma unroll
        for (int fn = 0; fn < 4; ++fn) {
            const int r = wn * 64 + fn * 16 + lane15;
            bf[fn] = *(const s16x8*)&sB[r * 32 + ((q ^ fl) << 3)];
        }
        #pragma unroll
        for (int fm = 0; fm < 4; ++fm)
            #pragma unroll
            for (int fn = 0; fn < 4; ++fn)
                acc[fm][fn] = __builtin_amdgcn_mfma_f32_16x16x32_bf16(af[fm], bf[fn], acc[fm][fn], 0, 0, 0);
        __syncthreads();
    }

    // D rows = n (j,k), cols = i.  4 consecutive k per lane-reg -> 8B NHWC stores.
    #pragma unroll
    for (int fm = 0; fm < 4; ++fm) {
        const int nbase = n0 + wm * 64 + fm * 16;
        const int j = nbase >> 5;
        const int k0 = (nbase & 31) + q * 4;
        #pragma unroll
        for (int fn = 0; fn < 4; ++fn) {
            const int i = i0 + wn * 64 + fn * 16 + lane15;
            s16x4 p;
            #pragma unroll
            for (int r = 0; r < 4; ++r) p[r] = (short)f2b(acc[fm][fn][r]);
            *(s16x4*)&X[(size_t)j * 32768 + i * 32 + k0] = p;
        }
    }
}

// ---------- conv 3x3 SAME + bias + leaky, NHWC in, row-pipelined ring buffer ----------
// Tile 128x8, ring of 4 row-buffers (136 px x 32 c bf16 = 8704B each).
template <bool FP32OUT>
__global__ __launch_bounds__(256, 4) void conv_kernel(const short* __restrict__ in,
                                                      const float* __restrict__ Wr,
                                                      const float* __restrict__ bias,
                                                      void* __restrict__ outv) {
    __shared__ short tile[4 * 136 * 32];   // slot*4352 + px*32 + c (slot-swizzled)
    const int tid = threadIdx.x;
    const int w = tid >> 6, lane = tid & 63, lane15 = lane & 15, q = lane >> 4;
    const int bx = blockIdx.x, by = blockIdx.y;
    const int x0 = bx * 128, y0 = by * 8;

    // A-fragments (weights): A[o][c], o = mf*16+lane15, c = q*8+e
    s16x8 aw[9][2];
    #pragma unroll
    for (int t = 0; t < 9; ++t)
        #pragma unroll
        for (int mf = 0; mf < 2; ++mf) {
            const int o = mf * 16 + lane15;
            const int c0 = q * 8;
            s16x8 a;
            #pragma unroll
            for (int e = 0; e < 8; ++e)
                a[e] = (short)f2b(Wr[(o * 32 + c0 + e) * 9 + t]);
            aw[t][mf] = a;
        }

    // zero halo columns once (persist across ring reuse; stage skips OOB gx)
    if (bx == 0 && tid < 16) *((s16x8*)&tile[(tid >> 2) * 4352] + (tid & 3)) = (s16x8)0;
    if (bx == 7 && tid < 16) *((s16x8*)&tile[(tid >> 2) * 4352 + 129 * 32] + (tid & 3)) = (s16x8)0;

    auto stage = [&](int ry) {
        const int gy = y0 - 1 + ry;
        char* base = (char*)&tile[(ry & 3) * 4352];
        if ((unsigned)gy < 1024u) {
            #pragma unroll
            for (int it = 0; it < 3; ++it) {
                const int idx = it * 256 + tid;
                if (idx < 544) {
                    const int px = idx >> 2, sseg = idx & 3;
                    const int gx = x0 - 1 + px;
                    if ((unsigned)gx < 1024u)
                        gload16(&in[(size_t)((gy << 10) + gx) * 32 + ((sseg ^ swz(px)) << 3)],
                                base + (it * 256 + w * 64) * 16);
                }
            }
        } else {
            s16x8* b8 = (s16x8*)base;
            for (int idx = tid; idx < 544; idx += 256) b8[idx] = (s16x8)0;
        }
    };

    stage(0); stage(1); stage(2);
    __syncthreads();

    for (int oy = 0; oy < 8; ++oy) {
        if (oy <= 6) stage(oy + 3);          // prefetch next row into free ring slot

        f32x4 acc[2][2];
        acc[0][0] = (f32x4)0; acc[0][1] = (f32x4)0;
        acc[1][0] = (f32x4)0; acc[1][1] = (f32x4)0;
        #pragma unroll
        for (int dy = 0; dy < 3; ++dy) {
            const short* rb = &tile[((oy + dy) & 3) * 4352];
            #pragma unroll
            for (int dx = 0; dx < 3; ++dx) {
                const int fl = swz(lane15 + dx);
                #pragma unroll
                for (int nfl = 0; nfl < 2; ++nfl) {
                    const int px = w * 32 + nfl * 16 + lane15 + dx;
                    const s16x8 bfr = *(const s16x8*)&rb[px * 32 + ((q ^ fl) << 3)];
                    acc[nfl][0] = __builtin_amdgcn_mfma_f32_16x16x32_bf16(aw[dy * 3 + dx][0], bfr, acc[nfl][0], 0, 0, 0);
                    acc[nfl][1] = __builtin_amdgcn_mfma_f32_16x16x32_bf16(aw[dy * 3 + dx][1], bfr, acc[nfl][1], 0, 0, 0);
                }
            }
        }

        const int gy = y0 + oy;
        #pragma unroll
        for (int mf = 0; mf < 2; ++mf) {
            const int o4 = mf * 16 + q * 4;                // D rows = o
            const f32x4 bb = *(const f32x4*)&bias[o4];
            #pragma unroll
            for (int nfl = 0; nfl < 2; ++nfl) {
                const int gx = x0 + w * 32 + nfl * 16 + lane15;   // D col = pixel
                f32x4 v = acc[nfl][mf];
                #pragma unroll
                for (int r = 0; r < 4; ++r) {
                    v[r] += bb[r];
                    v[r] = v[r] >= 0.f ? v[r] : 0.01f * v[r];
                }
                const size_t off = (((size_t)gy << 10) + gx) * 32 + o4;
                if (FP32OUT) {
                    *(f32x4*)((float*)outv + off) = v;
                } else {
                    s16x4 p;
                    #pragma unroll
                    for (int r = 0; r < 4; ++r) p[r] = (short)f2b(v[r]);
                    *(s16x4*)((short*)outv + off) = p;
                }
            }
        }
        __syncthreads();   // drains prefetch (vmcnt) + protects ring slot reuse
    }
}

extern "C" void kernel_launch(void* const* d_in, const int* in_sizes, int n_in,
                              void* d_out, int out_size, void* d_ws, size_t ws_size,
                              hipStream_t stream) {
    const float* Z1 = (const float*)d_in[0];
    const float* Z2 = (const float*)d_in[1];
    const float* Z3 = (const float*)d_in[2];
    const float* W1 = (const float*)d_in[3];
    const float* b1 = (const float*)d_in[4];
    const float* W2 = (const float*)d_in[5];
    const float* b2 = (const float*)d_in[6];

    // d_out (134.2MB) as scratch: [X nhwc bf16 67.1MB][Bv2 16.8MB][Z1r 0.5MB]
    short* X   = (short*)d_out;
    short* Bv2 = X + 33554432;
    short* Z1r = Bv2 + 8388608;
    short* y1  = (short*)d_ws;           // 67.1MB NHWC bf16

    v_kernel  <<<1024, 256, 0, stream>>>(Z2, Z3, Bv2);
    z1r_kernel<<<64,   256, 0, stream>>>(Z1, Z1r);
    gemm_kernel<<<2048, 256, 0, stream>>>(Bv2, Z1r, X);
    conv_kernel<false><<<dim3(8, 128), 256, 0, stream>>>(X,  W1, b1, y1);
    conv_kernel<true> <<<dim3(8, 128), 256, 0, stream>>>(y1, W2, b2, d_out);
}

// Round 4
// 140.409 us; speedup vs baseline: 8.2320x; 1.4469x over previous
//
#include <hip/hip_runtime.h>

typedef short  s16x4 __attribute__((ext_vector_type(4)));
typedef short  s16x8 __attribute__((ext_vector_type(8)));
typedef float  f32x4 __attribute__((ext_vector_type(4)));

__device__ __forceinline__ unsigned short f2b(float f) {
    unsigned u = __float_as_uint(f);
    u = u + 0x7FFFu + ((u >> 16) & 1u);   // RNE
    return (unsigned short)(u >> 16);
}

__device__ __forceinline__ void gload16(const void* g, void* l) {
    __builtin_amdgcn_global_load_lds((const __attribute__((address_space(1))) unsigned*)g,
                                     (__attribute__((address_space(3))) unsigned*)l,
                                     16, 0, 0);
}

// slot swizzle, period 16 in px: spreads per-pixel 16B channel-slots across banks
__device__ __forceinline__ int swz(int x) { return (x ^ (x >> 2)) & 3; }

// ---------- Bv2[(j*32+k)*256 + a*16+b] = sum_c Z2[b,j,c] * Z3[c,k,a]  (bf16) ----------
__global__ __launch_bounds__(256) void v_kernel(const float* __restrict__ Z2,
                                                const float* __restrict__ Z3,
                                                short* __restrict__ Bv2) {
    __shared__ float z3t[8192];   // [c][a][k]
    __shared__ float z2s[256];    // [b][c]
    const int tid = threadIdx.x, j = blockIdx.x;
    for (int t = tid; t < 8192; t += 256) {
        float v = Z3[t];                     // Z3[c,k,a] flat = c*512 + k*16 + a
        int c = t >> 9, k = (t >> 4) & 31, a = t & 15;
        z3t[c * 512 + a * 32 + k] = v;
    }
    z2s[tid] = Z2[(tid >> 4) * 16384 + j * 16 + (tid & 15)];
    __syncthreads();
    const int a = tid >> 4, b = tid & 15;
    float z2r[16];
    #pragma unroll
    for (int c = 0; c < 16; ++c) z2r[c] = z2s[b * 16 + c];
    float s[32];
    #pragma unroll
    for (int k = 0; k < 32; ++k) s[k] = 0.f;
    #pragma unroll
    for (int c = 0; c < 16; ++c) {
        #pragma unroll
        for (int k4 = 0; k4 < 8; ++k4) {
            f32x4 v = *(const f32x4*)&z3t[c * 512 + a * 32 + k4 * 4];
            #pragma unroll
            for (int r = 0; r < 4; ++r) s[k4 * 4 + r] += z2r[c] * v[r];
        }
    }
    #pragma unroll
    for (int k = 0; k < 32; ++k)
        Bv2[(size_t)(j * 32 + k) * 256 + tid] = (short)f2b(s[k]);
}

// ---------- Z1r[i*256 + a*16+b] = Z1[a,i,b]  (bf16) ----------
__global__ __launch_bounds__(256) void z1r_kernel(const float* __restrict__ Z1,
                                                  short* __restrict__ Z1r) {
    __shared__ float z1s[4096];
    const int tid = threadIdx.x, i0 = blockIdx.x * 16;
    #pragma unroll
    for (int a = 0; a < 16; ++a)
        z1s[a * 256 + tid] = Z1[a * 16384 + i0 * 16 + tid];
    __syncthreads();
    #pragma unroll
    for (int il = 0; il < 16; ++il)
        Z1r[(size_t)(i0 + il) * 256 + tid] =
            (short)f2b(z1s[(tid >> 4) * 256 + il * 16 + (tid & 15)]);
}

// ---------- X_nhwc[j][i][k] = sum_ab Bv2[(j*32+k)][ab] * Z1r[i][ab]  (bf16 MFMA) ----------
__global__ __launch_bounds__(256) void gemm_kernel(const short* __restrict__ Bv2,
                                                   const short* __restrict__ Z1r,
                                                   short* __restrict__ X) {
    __shared__ short sA[128 * 32];
    __shared__ short sB[128 * 32];
    const int tid = threadIdx.x;
    const int w = tid >> 6, lane = tid & 63, lane15 = lane & 15, q = lane >> 4;
    const int wm = w >> 1, wn = w & 1;
    const int bid = blockIdx.x;
    const int l = (bid & 7) * 256 + (bid >> 3);      // XCD-chunked swizzle
    const int n0 = (l >> 3) * 128, i0 = (l & 7) * 128;
    const int rs = lane >> 2, sp = lane & 3;
    const int scol = (sp ^ swz(rs)) << 3;
    const int fl = swz(lane15);

    f32x4 acc[4][4];
    #pragma unroll
    for (int a = 0; a < 4; ++a)
        #pragma unroll
        for (int b = 0; b < 4; ++b) acc[a][b] = (f32x4)0;

    for (int kk = 0; kk < 256; kk += 32) {
        gload16(&Bv2[(size_t)(n0 + w * 16 + rs) * 256 + kk + scol],       (char*)sA + w * 1024);
        gload16(&Bv2[(size_t)(n0 + (w + 4) * 16 + rs) * 256 + kk + scol], (char*)sA + (w + 4) * 1024);
        gload16(&Z1r[(size_t)(i0 + w * 16 + rs) * 256 + kk + scol],       (char*)sB + w * 1024);
        gload16(&Z1r[(size_t)(i0 + (w + 4) * 16 + rs) * 256 + kk + scol], (char*)sB + (w + 4) * 1024);
        __syncthreads();
        s16x8 af[4], bf[4];
        #pragma unroll
        for (int fm = 0; fm < 4; ++fm) {
            const int r = wm * 64 + fm * 16 + lane15;
            af[fm] = *(const s16x8*)&sA[r * 32 + ((q ^ fl) << 3)];
        }
        #pragma unroll
        for (int fn = 0; fn < 4; ++fn) {
            const int r = wn * 64 + fn * 16 + lane15;
            bf[fn] = *(const s16x8*)&sB[r * 32 + ((q ^ fl) << 3)];
        }
        #pragma unroll
        for (int fm = 0; fm < 4; ++fm)
            #pragma unroll
            for (int fn = 0; fn < 4; ++fn)
                acc[fm][fn] = __builtin_amdgcn_mfma_f32_16x16x32_bf16(af[fm], bf[fn], acc[fm][fn], 0, 0, 0);
        __syncthreads();
    }

    #pragma unroll
    for (int fm = 0; fm < 4; ++fm) {
        const int nbase = n0 + wm * 64 + fm * 16;
        const int j = nbase >> 5;
        const int k0 = (nbase & 31) + q * 4;
        #pragma unroll
        for (int fn = 0; fn < 4; ++fn) {
            const int i = i0 + wn * 64 + fn * 16 + lane15;
            s16x4 p;
            #pragma unroll
            for (int r = 0; r < 4; ++r) p[r] = (short)f2b(acc[fm][fn][r]);
            *(s16x4*)&X[(size_t)j * 32768 + i * 32 + k0] = p;
        }
    }
}

// ---------- fused conv1+leaky+conv2+leaky, NHWC, row-pipelined, y1 in LDS ----------
// Out tile 128x16. X ring: 4 rows x 146 px; y1 ring: 3 rows x 144 px.
#define XW 146
#define XROW (XW * 32)          // shorts per X ring row (9344 B)
#define YROW (144 * 32)         // shorts per y1 ring row (9216 B)
__global__ __launch_bounds__(256, 2) void fconv_kernel(const short* __restrict__ in,
                                                       const float* __restrict__ W1,
                                                       const float* __restrict__ b1,
                                                       const float* __restrict__ W2,
                                                       const float* __restrict__ b2,
                                                       float* __restrict__ out) {
    __shared__ short xr[4 * XROW];   // 37376 B
    __shared__ short yr[3 * YROW];   // 27648 B
    const int tid = threadIdx.x;
    const int w = tid >> 6, lane = tid & 63, lane15 = lane & 15, q = lane >> 4;
    const int bx = blockIdx.x, by = blockIdx.y;
    const int x0 = bx * 128, y0 = by * 16;
    const int gx0 = x0 - 9;          // X stage origin (px 0)

    // Both convs' weight A-frags in registers: A[o][c], o=mf*16+lane15, c=q*8+e
    s16x8 aw1[9][2], aw2[9][2];
    #pragma unroll
    for (int t = 0; t < 9; ++t)
        #pragma unroll
        for (int mf = 0; mf < 2; ++mf) {
            const int o = mf * 16 + lane15, c0 = q * 8;
            s16x8 a1, a2;
            #pragma unroll
            for (int e = 0; e < 8; ++e) {
                a1[e] = (short)f2b(W1[(o * 32 + c0 + e) * 9 + t]);
                a2[e] = (short)f2b(W2[(o * 32 + c0 + e) * 9 + t]);
            }
            aw1[t][mf] = a1; aw2[t][mf] = a2;
        }
    f32x4 bb1[2], bb2[2];
    #pragma unroll
    for (int mf = 0; mf < 2; ++mf) {
        bb1[mf] = *(const f32x4*)&b1[mf * 16 + q * 4];
        bb2[mf] = *(const f32x4*)&b2[mf * 16 + q * 4];
    }

    // persistent zeros for x-halo columns at image edges
    if (bx == 0 || bx == 7) {
        s16x8* p = (s16x8*)xr;
        for (int i = tid; i < 4 * XW * 4; i += 256) p[i] = (s16x8)0;
    }
    __syncthreads();

    auto stage = [&](int rr) {                       // X image row y0+rr -> slot (rr+2)&3
        const int gy = y0 + rr;
        char* base = (char*)&xr[((rr + 2) & 3) * XROW];
        if ((unsigned)gy < 1024u) {
            #pragma unroll
            for (int it = 0; it < 3; ++it) {
                const int idx = it * 256 + tid;
                if (idx < XW * 4) {
                    const int px = idx >> 2, sseg = idx & 3;
                    const int gx = gx0 + px;
                    if ((unsigned)gx < 1024u)
                        gload16(&in[(size_t)((gy << 10) + gx) * 32 + ((sseg ^ swz(px)) << 3)],
                                base + (it * 256 + w * 64) * 16);
                }
            }
        } else {
            s16x8* b8 = (s16x8*)base;
            for (int idx = tid; idx < XW * 4; idx += 256) b8[idx] = (s16x8)0;
        }
    };

    auto y1_store = [&](const f32x4* acc, int n, int ysl) {
        const int pfx = n * 16 + lane15;
        const int gx1 = x0 - 8 + pfx;
        const bool valid = (unsigned)gx1 < 1024u;    // conv2 zero-pads y1 at image edge
        #pragma unroll
        for (int mf = 0; mf < 2; ++mf) {
            s16x4 p;
            #pragma unroll
            for (int r = 0; r < 4; ++r) {
                float f = acc[mf][r] + bb1[mf][r];
                f = f >= 0.f ? f : 0.01f * f;
                p[r] = valid ? (short)f2b(f) : (short)0;
            }
            const int u = mf * 4 + q, s = u >> 1, low = u & 1;
            *(s16x4*)&yr[ysl + pfx * 32 + ((s ^ swz(pfx)) << 3) + low * 4] = p;
        }
    };

    auto compute_y1 = [&](int ry) {                  // y1 image row y0+ry -> slot (ry+3)%3
        const int gy1 = y0 + ry;
        const int ysl = ((ry + 3) % 3) * YROW;
        if ((unsigned)gy1 < 1024u) {
            int xs[3];
            #pragma unroll
            for (int dy = 0; dy < 3; ++dy) xs[dy] = ((ry - 1 + dy + 2) & 3) * XROW;
            f32x4 a0[2], a1[2], a2[2];
            #pragma unroll
            for (int mf = 0; mf < 2; ++mf) { a0[mf] = (f32x4)0; a1[mf] = (f32x4)0; a2[mf] = (f32x4)0; }
            #pragma unroll
            for (int dy = 0; dy < 3; ++dy)
                #pragma unroll
                for (int dx = 0; dx < 3; ++dx) {
                    const int t = dy * 3 + dx;
                    {
                        const int lpx = (w * 2) * 16 + lane15 + dx;
                        const s16x8 bfr = *(const s16x8*)&xr[xs[dy] + lpx * 32 + ((q ^ swz(lpx)) << 3)];
                        a0[0] = __builtin_amdgcn_mfma_f32_16x16x32_bf16(aw1[t][0], bfr, a0[0], 0, 0, 0);
                        a0[1] = __builtin_amdgcn_mfma_f32_16x16x32_bf16(aw1[t][1], bfr, a0[1], 0, 0, 0);
                    }
                    {
                        const int lpx = (w * 2 + 1) * 16 + lane15 + dx;
                        const s16x8 bfr = *(const s16x8*)&xr[xs[dy] + lpx * 32 + ((q ^ swz(lpx)) << 3)];
                        a1[0] = __builtin_amdgcn_mfma_f32_16x16x32_bf16(aw1[t][0], bfr, a1[0], 0, 0, 0);
                        a1[1] = __builtin_amdgcn_mfma_f32_16x16x32_bf16(aw1[t][1], bfr, a1[1], 0, 0, 0);
                    }
                    if (w == 0) {                    // 9th tile (y1 width 144 = 9x16)
                        const int lpx = 128 + lane15 + dx;
                        const s16x8 bfr = *(const s16x8*)&xr[xs[dy] + lpx * 32 + ((q ^ swz(lpx)) << 3)];
                        a2[0] = __builtin_amdgcn_mfma_f32_16x16x32_bf16(aw1[t][0], bfr, a2[0], 0, 0, 0);
                        a2[1] = __builtin_amdgcn_mfma_f32_16x16x32_bf16(aw1[t][1], bfr, a2[1], 0, 0, 0);
                    }
                }
            y1_store(a0, w * 2, ysl);
            y1_store(a1, w * 2 + 1, ysl);
            if (w == 0) y1_store(a2, 8, ysl);
        } else {                                     // conv2 zero-padding row
            s16x8* b8 = (s16x8*)&yr[ysl];
            for (int idx = tid; idx < 576; idx += 256) b8[idx] = (s16x8)0;
        }
    };

    auto compute_out = [&](int r) {                  // out image row y0+r
        const int gy = y0 + r;
        int ys[3];
        #pragma unroll
        for (int dy = 0; dy < 3; ++dy) ys[dy] = ((r - 1 + dy + 3) % 3) * YROW;
        f32x4 acc[2][2];
        #pragma unroll
        for (int nf = 0; nf < 2; ++nf) { acc[nf][0] = (f32x4)0; acc[nf][1] = (f32x4)0; }
        #pragma unroll
        for (int dy = 0; dy < 3; ++dy)
            #pragma unroll
            for (int dx = 0; dx < 3; ++dx) {
                const int t = dy * 3 + dx;
                #pragma unroll
                for (int nf = 0; nf < 2; ++nf) {
                    const int lpx = w * 32 + nf * 16 + lane15 + dx + 7;
                    const s16x8 bfr = *(const s16x8*)&yr[ys[dy] + lpx * 32 + ((q ^ swz(lpx)) << 3)];
                    acc[nf][0] = __builtin_amdgcn_mfma_f32_16x16x32_bf16(aw2[t][0], bfr, acc[nf][0], 0, 0, 0);
                    acc[nf][1] = __builtin_amdgcn_mfma_f32_16x16x32_bf16(aw2[t][1], bfr, acc[nf][1], 0, 0, 0);
                }
            }
        #pragma unroll
        for (int mf = 0; mf < 2; ++mf) {
            const int o4 = mf * 16 + q * 4;
            #pragma unroll
            for (int nf = 0; nf < 2; ++nf) {
                const int gx = x0 + w * 32 + nf * 16 + lane15;
                f32x4 v = acc[nf][mf];
                #pragma unroll
                for (int r4 = 0; r4 < 4; ++r4) {
                    v[r4] += bb2[mf][r4];
                    v[r4] = v[r4] >= 0.f ? v[r4] : 0.01f * v[r4];
                }
                __builtin_nontemporal_store(v, (f32x4*)&out[(((size_t)gy << 10) + gx) * 32 + o4]);
            }
        }
    };

    // prologue
    stage(-2); stage(-1); stage(0); stage(1);
    __syncthreads();
    compute_y1(-1);
    compute_y1(0);
    __syncthreads();

    // main pipeline: stage(r+2) || out(r-1) | barrier | y1(r+1) | barrier
    for (int r = 0; r < 16; ++r) {
        stage(r + 2);
        if (r > 0) compute_out(r - 1);
        __syncthreads();
        compute_y1(r + 1);
        __syncthreads();
    }
    compute_out(15);
}

extern "C" void kernel_launch(void* const* d_in, const int* in_sizes, int n_in,
                              void* d_out, int out_size, void* d_ws, size_t ws_size,
                              hipStream_t stream) {
    const float* Z1 = (const float*)d_in[0];
    const float* Z2 = (const float*)d_in[1];
    const float* Z3 = (const float*)d_in[2];
    const float* W1 = (const float*)d_in[3];
    const float* b1 = (const float*)d_in[4];
    const float* W2 = (const float*)d_in[5];
    const float* b2 = (const float*)d_in[6];

    // X (NHWC bf16, 67.1 MB) in ws; Bv2/Z1r in d_out-as-scratch (dead before fconv writes d_out)
    short* X   = (short*)d_ws;
    short* Bv2 = (short*)d_out;
    short* Z1r = Bv2 + 8388608;

    v_kernel  <<<1024, 256, 0, stream>>>(Z2, Z3, Bv2);
    z1r_kernel<<<64,   256, 0, stream>>>(Z1, Z1r);
    gemm_kernel<<<2048, 256, 0, stream>>>(Bv2, Z1r, X);
    fconv_kernel<<<dim3(8, 64), 256, 0, stream>>>(X, W1, b1, W2, b2, (float*)d_out);
}